// Round 1
// baseline (360.169 us; speedup 1.0000x reference)
//
#include <hip/hip_runtime.h>
#include <hip/hip_bf16.h>

#define NN 8192
#define KIN 512
#define KOUT 256
#define ALPHA 0.2f

typedef __bf16 bf16x8 __attribute__((ext_vector_type(8)));
typedef float f32x4 __attribute__((ext_vector_type(4)));
typedef unsigned short ushort8_t __attribute__((ext_vector_type(8)));
typedef unsigned short ushort4_t __attribute__((ext_vector_type(4)));

__device__ __forceinline__ float lrelu(float x) { return x > 0.f ? x : ALPHA * x; }

__device__ __forceinline__ unsigned short f2bf(float f) {
  union { float f; unsigned u; } v; v.f = f;
  unsigned r = v.u + 0x7fffu + ((v.u >> 16) & 1u);  // RNE to bf16
  return (unsigned short)(r >> 16);
}
__device__ __forceinline__ float bf2f(unsigned short b) {
  union { unsigned u; float f; } v; v.u = ((unsigned)b) << 16;
  return v.f;
}

// ---------------- k1: Wh = h @ W (fp32), fused src/dst, store Wh as bf16 ----
// tile 32 rows x 256 cols, 512 threads (8 waves; wave owns 4 rows, lane owns 4 cols)
__global__ __launch_bounds__(512) void k_wh(const float* __restrict__ h,
                                            const float* __restrict__ W,
                                            const float* __restrict__ a1,
                                            const float* __restrict__ a2,
                                            unsigned short* __restrict__ WhB,
                                            float* __restrict__ src,
                                            float* __restrict__ dstv) {
  __shared__ float sA[16][36];    // [k][row]
  __shared__ float sB[16][260];   // [k][col]
  const int tid = threadIdx.x;
  const int wave = tid >> 6;
  const int lane = tid & 63;
  const int bm = blockIdx.x * 32;
  const int arow = tid >> 4;        // 0..31
  const int akk = tid & 15;
  const int bkr = tid >> 5;         // 0..15
  const int bc = (tid & 31) * 8;
  float acc[4][4] = {};
  for (int k0 = 0; k0 < KIN; k0 += 16) {
    float av = h[(size_t)(bm + arow) * KIN + k0 + akk];
    const float4* wp = (const float4*)(W + (size_t)(k0 + bkr) * KOUT + bc);
    float4 w0 = wp[0], w1 = wp[1];
    __syncthreads();
    sA[akk][arow] = av;
    *(float4*)&sB[bkr][bc] = w0;
    *(float4*)&sB[bkr][bc + 4] = w1;
    __syncthreads();
#pragma unroll
    for (int k = 0; k < 16; ++k) {
      float4 a4 = *(const float4*)&sA[k][wave * 4];
      float4 b4 = *(const float4*)&sB[k][lane * 4];
      float aa[4] = {a4.x, a4.y, a4.z, a4.w};
      float bb[4] = {b4.x, b4.y, b4.z, b4.w};
#pragma unroll
      for (int i = 0; i < 4; ++i)
#pragma unroll
        for (int jj = 0; jj < 4; ++jj)
          acc[i][jj] = fmaf(aa[i], bb[jj], acc[i][jj]);
    }
  }
  // epilogue: src/dst partials + reduce over 64 lanes
  float4 a1v = *(const float4*)(a1 + lane * 4);
  float4 a2v = *(const float4*)(a2 + lane * 4);
  float sp[4], dp[4];
#pragma unroll
  for (int i = 0; i < 4; ++i) {
    sp[i] = acc[i][0] * a1v.x + acc[i][1] * a1v.y + acc[i][2] * a1v.z + acc[i][3] * a1v.w;
    dp[i] = acc[i][0] * a2v.x + acc[i][1] * a2v.y + acc[i][2] * a2v.z + acc[i][3] * a2v.w;
  }
#pragma unroll
  for (int off = 32; off >= 1; off >>= 1) {
#pragma unroll
    for (int i = 0; i < 4; ++i) {
      sp[i] += __shfl_xor(sp[i], off);
      dp[i] += __shfl_xor(dp[i], off);
    }
  }
  if (lane == 0) {
#pragma unroll
    for (int i = 0; i < 4; ++i) {
      src[bm + wave * 4 + i] = sp[i];
      dstv[bm + wave * 4 + i] = dp[i];
    }
  }
  // store Wh as bf16 (row-major), coalesced ushort4 stores
#pragma unroll
  for (int i = 0; i < 4; ++i) {
    ushort4_t pk;
#pragma unroll
    for (int jj = 0; jj < 4; ++jj) pk[jj] = f2bf(acc[i][jj]);
    *(ushort4_t*)(WhB + (size_t)(bm + wave * 4 + i) * KOUT + lane * 4) = pk;
  }
}

// ---------------- k_tr: WhT[c][r] = WhB[r][c], 64x64 tiles ----------------
__global__ __launch_bounds__(256) void k_tr(const unsigned short* __restrict__ WhB,
                                            unsigned short* __restrict__ WhT) {
  __shared__ unsigned int sX[64][65];
  const int t = threadIdx.x;
  const int r0 = (blockIdx.x & 127) * 64;
  const int c0 = (blockIdx.x >> 7) * 64;
  const int rr = t >> 2;
  const int cq = (t & 3) * 16;
  const ushort8_t* p = (const ushort8_t*)(WhB + (size_t)(r0 + rr) * KOUT + c0 + cq);
  ushort8_t v0 = p[0], v1 = p[1];
#pragma unroll
  for (int i = 0; i < 8; ++i) {
    sX[rr][cq + i] = v0[i];
    sX[rr][cq + 8 + i] = v1[i];
  }
  __syncthreads();
  const int cc = t >> 2;
  const int r8 = (t & 3) * 16;
  ushort8_t o0, o1;
#pragma unroll
  for (int i = 0; i < 8; ++i) {
    o0[i] = (unsigned short)sX[r8 + i][cc];
    o1[i] = (unsigned short)sX[r8 + 8 + i][cc];
  }
  ushort8_t* q = (ushort8_t*)(WhT + (size_t)(c0 + cc) * NN + r0 + r8);
  q[0] = o0;
  q[1] = o1;
}

// ---------------- k_dmax: D = max(dst) -----------------------------------
__global__ __launch_bounds__(256) void k_dmax(const float* __restrict__ dstv,
                                              float* __restrict__ Dp) {
  __shared__ float red[256];
  const int t = threadIdx.x;
  float m = -3e38f;
  for (int i = t; i < NN; i += 256) m = fmaxf(m, dstv[i]);
  red[t] = m;
  __syncthreads();
  for (int s = 128; s >= 1; s >>= 1) {
    if (t < s) red[t] = fmaxf(red[t], red[t + s]);
    __syncthreads();
  }
  if (t == 0) *Dp = red[0];
}

// ---------------- k_attn: fused masked softmax + attn@Wh + elu ------------
// block: 32 rows, 512 threads (8 waves), BK=32; wave owns 32x32 output slice
__global__ __launch_bounds__(512) void k_attn(const int* __restrict__ adj,
                                              const unsigned short* __restrict__ WhT,
                                              const float* __restrict__ src,
                                              const float* __restrict__ dstv,
                                              const float* __restrict__ Dp,
                                              float* __restrict__ out) {
  __shared__ unsigned short sAw[32][40];   // weights tile [row][k]
  __shared__ unsigned short sB[256][40];   // Wh tile [col][k]
  __shared__ float sL[32];
  const int tid = threadIdx.x;
  const int lane = tid & 63;
  const int wave = tid >> 6;
  const int r0 = blockIdx.x * 32;
  const float D = *Dp;
  // A-generation assignment: 16 groups of 32 lanes; group rr handles rows rr, rr+16
  const int j = tid & 31;
  const int rr = tid >> 5;  // 0..15
  const float s0 = src[r0 + rr];
  const float s1 = src[r0 + rr + 16];
  const float c0 = lrelu(s0 + D);
  const float c1 = lrelu(s1 + D);
  float ls0 = 0.f, ls1 = 0.f;
  const int* adjp0 = adj + (size_t)(r0 + rr) * NN;
  const int* adjp1 = adj + (size_t)(r0 + rr + 16) * NN;
  // B staging: thread pair per column
  const int bcol = tid >> 1;
  const int bq = (tid & 1) * 16;
  const unsigned short* wtp = WhT + (size_t)bcol * NN + bq;
  unsigned short* sBw = &sB[bcol][bq];
  // MFMA fragment addressing
  const int fr = lane & 15;
  const int fq = lane >> 4;  // 0..3
  const unsigned short* aP0 = &sAw[fr][fq * 8];
  const unsigned short* aP1 = &sAw[16 + fr][fq * 8];
  const unsigned short* bP0 = &sB[wave * 32 + fr][fq * 8];
  const unsigned short* bP1 = &sB[wave * 32 + 16 + fr][fq * 8];
  f32x4 acc00 = {0.f, 0.f, 0.f, 0.f};
  f32x4 acc01 = acc00, acc10 = acc00, acc11 = acc00;
  for (int k0 = 0; k0 < NN; k0 += 32) {
    const int ad0 = adjp0[k0 + j];
    const int ad1 = adjp1[k0 + j];
    const float dj = dstv[k0 + j];
    const ushort8_t b0 = *(const ushort8_t*)(wtp + k0);
    const ushort8_t b1 = *(const ushort8_t*)(wtp + k0 + 8);
    const float e0 = lrelu(s0 + dj) - c0;  // <= 0 always (c uses global dst max)
    const float e1 = lrelu(s1 + dj) - c1;
    const unsigned short w0 = (ad0 > 0) ? f2bf(__expf(e0)) : (unsigned short)0;
    const unsigned short w1 = (ad1 > 0) ? f2bf(__expf(e1)) : (unsigned short)0;
    ls0 += bf2f(w0);  // accumulate the bf16-rounded weight -> consistent normalization
    ls1 += bf2f(w1);
    __syncthreads();  // previous iteration's fragment reads complete
    sAw[rr][j] = w0;
    sAw[rr + 16][j] = w1;
    *(ushort8_t*)sBw = b0;
    *(ushort8_t*)(sBw + 8) = b1;
    __syncthreads();  // tiles visible
    bf16x8 af0 = __builtin_bit_cast(bf16x8, *(const ushort8_t*)aP0);
    bf16x8 af1 = __builtin_bit_cast(bf16x8, *(const ushort8_t*)aP1);
    bf16x8 bv0 = __builtin_bit_cast(bf16x8, *(const ushort8_t*)bP0);
    bf16x8 bv1 = __builtin_bit_cast(bf16x8, *(const ushort8_t*)bP1);
    acc00 = __builtin_amdgcn_mfma_f32_16x16x32_bf16(af0, bv0, acc00, 0, 0, 0);
    acc01 = __builtin_amdgcn_mfma_f32_16x16x32_bf16(af0, bv1, acc01, 0, 0, 0);
    acc10 = __builtin_amdgcn_mfma_f32_16x16x32_bf16(af1, bv0, acc10, 0, 0, 0);
    acc11 = __builtin_amdgcn_mfma_f32_16x16x32_bf16(af1, bv1, acc11, 0, 0, 0);
  }
  // reduce row sums across the 32 j-lanes (within each 32-lane half)
#pragma unroll
  for (int off = 1; off <= 16; off <<= 1) {
    ls0 += __shfl_xor(ls0, off);
    ls1 += __shfl_xor(ls1, off);
  }
  if (j == 0) {
    sL[rr] = ls0;
    sL[rr + 16] = ls1;
  }
  __syncthreads();
  // epilogue: divide by row sum, ELU, store
  const f32x4 accs[2][2] = {{acc00, acc01}, {acc10, acc11}};
#pragma unroll
  for (int mr = 0; mr < 2; ++mr) {
#pragma unroll
    for (int r = 0; r < 4; ++r) {
      const int row = mr * 16 + fq * 4 + r;
      const float l = sL[row];
#pragma unroll
      for (int nc = 0; nc < 2; ++nc) {
        const int col = wave * 32 + nc * 16 + fr;
        float v = accs[mr][nc][r] / l;
        v = v > 0.f ? v : __expf(v) - 1.f;
        out[(size_t)(r0 + row) * KOUT + col] = v;
      }
    }
  }
}

extern "C" void kernel_launch(void* const* d_in, const int* in_sizes, int n_in,
                              void* d_out, int out_size, void* d_ws, size_t ws_size,
                              hipStream_t stream) {
  const float* h = (const float*)d_in[0];
  const int* adj = (const int*)d_in[1];
  const float* W = (const float*)d_in[2];
  const float* a1 = (const float*)d_in[3];
  const float* a2 = (const float*)d_in[4];
  float* out = (float*)d_out;

  unsigned short* WhB = (unsigned short*)d_ws;            // 8192*256 bf16 = 4 MB
  unsigned short* WhT = WhB + (size_t)NN * KOUT;          // 4 MB (transposed)
  float* src = (float*)(WhT + (size_t)NN * KOUT);         // 32 KB
  float* dstv = src + NN;                                 // 32 KB
  float* Dp = dstv + NN;                                  // 4 B

  hipLaunchKernelGGL(k_wh, dim3(NN / 32), dim3(512), 0, stream, h, W, a1, a2, WhB, src, dstv);
  hipLaunchKernelGGL(k_tr, dim3(512), dim3(256), 0, stream, WhB, WhT);
  hipLaunchKernelGGL(k_dmax, dim3(1), dim3(256), 0, stream, dstv, Dp);
  hipLaunchKernelGGL(k_attn, dim3(NN / 32), dim3(512), 0, stream, adj, WhT, src, dstv, Dp, out);
}

// Round 2
// 194.596 us; speedup vs baseline: 1.8509x; 1.8509x over previous
//
#include <hip/hip_runtime.h>
#include <hip/hip_bf16.h>

#define NN 8192
#define KIN 512
#define KOUT 256
#define ALPHA 0.2f
#define BK 64
#define NT (NN / BK)

typedef __bf16 bf16x8 __attribute__((ext_vector_type(8)));
typedef float f32x4 __attribute__((ext_vector_type(4)));
typedef unsigned short ushort8_t __attribute__((ext_vector_type(8)));
typedef unsigned short ushort4_t __attribute__((ext_vector_type(4)));

__device__ __forceinline__ float lrelu(float x) { return x > 0.f ? x : ALPHA * x; }

__device__ __forceinline__ unsigned short f2bf(float f) {
  union { float f; unsigned u; } v; v.f = f;
  unsigned r = v.u + 0x7fffu + ((v.u >> 16) & 1u);  // RNE to bf16
  return (unsigned short)(r >> 16);
}
__device__ __forceinline__ float bf2f(unsigned short b) {
  union { unsigned u; float f; } v; v.u = ((unsigned)b) << 16;
  return v.f;
}

// ---------------- k1: Wh = h @ W (fp32), fused src/dst, store Wh as bf16 ----
__global__ __launch_bounds__(512) void k_wh(const float* __restrict__ h,
                                            const float* __restrict__ W,
                                            const float* __restrict__ a1,
                                            const float* __restrict__ a2,
                                            unsigned short* __restrict__ WhB,
                                            float* __restrict__ src,
                                            float* __restrict__ dstv) {
  __shared__ float sA[16][36];    // [k][row]
  __shared__ float sB[16][260];   // [k][col]
  const int tid = threadIdx.x;
  const int wave = tid >> 6;
  const int lane = tid & 63;
  const int bm = blockIdx.x * 32;
  const int arow = tid >> 4;
  const int akk = tid & 15;
  const int bkr = tid >> 5;
  const int bc = (tid & 31) * 8;
  float acc[4][4] = {};
  for (int k0 = 0; k0 < KIN; k0 += 16) {
    float av = h[(size_t)(bm + arow) * KIN + k0 + akk];
    const float4* wp = (const float4*)(W + (size_t)(k0 + bkr) * KOUT + bc);
    float4 w0 = wp[0], w1 = wp[1];
    __syncthreads();
    sA[akk][arow] = av;
    *(float4*)&sB[bkr][bc] = w0;
    *(float4*)&sB[bkr][bc + 4] = w1;
    __syncthreads();
#pragma unroll
    for (int k = 0; k < 16; ++k) {
      float4 a4 = *(const float4*)&sA[k][wave * 4];
      float4 b4 = *(const float4*)&sB[k][lane * 4];
      float aa[4] = {a4.x, a4.y, a4.z, a4.w};
      float bb[4] = {b4.x, b4.y, b4.z, b4.w};
#pragma unroll
      for (int i = 0; i < 4; ++i)
#pragma unroll
        for (int jj = 0; jj < 4; ++jj)
          acc[i][jj] = fmaf(aa[i], bb[jj], acc[i][jj]);
    }
  }
  float4 a1v = *(const float4*)(a1 + lane * 4);
  float4 a2v = *(const float4*)(a2 + lane * 4);
  float sp[4], dp[4];
#pragma unroll
  for (int i = 0; i < 4; ++i) {
    sp[i] = acc[i][0] * a1v.x + acc[i][1] * a1v.y + acc[i][2] * a1v.z + acc[i][3] * a1v.w;
    dp[i] = acc[i][0] * a2v.x + acc[i][1] * a2v.y + acc[i][2] * a2v.z + acc[i][3] * a2v.w;
  }
#pragma unroll
  for (int off = 32; off >= 1; off >>= 1) {
#pragma unroll
    for (int i = 0; i < 4; ++i) {
      sp[i] += __shfl_xor(sp[i], off);
      dp[i] += __shfl_xor(dp[i], off);
    }
  }
  if (lane == 0) {
#pragma unroll
    for (int i = 0; i < 4; ++i) {
      src[bm + wave * 4 + i] = sp[i];
      dstv[bm + wave * 4 + i] = dp[i];
    }
  }
#pragma unroll
  for (int i = 0; i < 4; ++i) {
    ushort4_t pk;
#pragma unroll
    for (int jj = 0; jj < 4; ++jj) pk[jj] = f2bf(acc[i][jj]);
    *(ushort4_t*)(WhB + (size_t)(bm + wave * 4 + i) * KOUT + lane * 4) = pk;
  }
}

// ---------------- k_tr: WhT[c][r] = WhB[r][c] ----------------
__global__ __launch_bounds__(256) void k_tr(const unsigned short* __restrict__ WhB,
                                            unsigned short* __restrict__ WhT) {
  __shared__ unsigned int sX[64][65];
  const int t = threadIdx.x;
  const int r0 = (blockIdx.x & 127) * 64;
  const int c0 = (blockIdx.x >> 7) * 64;
  const int rr = t >> 2;
  const int cq = (t & 3) * 16;
  const ushort8_t* p = (const ushort8_t*)(WhB + (size_t)(r0 + rr) * KOUT + c0 + cq);
  ushort8_t v0 = p[0], v1 = p[1];
#pragma unroll
  for (int i = 0; i < 8; ++i) {
    sX[rr][cq + i] = v0[i];
    sX[rr][cq + 8 + i] = v1[i];
  }
  __syncthreads();
  const int cc = t >> 2;
  const int r8 = (t & 3) * 16;
  ushort8_t o0, o1;
#pragma unroll
  for (int i = 0; i < 8; ++i) {
    o0[i] = (unsigned short)sX[r8 + i][cc];
    o1[i] = (unsigned short)sX[r8 + 8 + i][cc];
  }
  ushort8_t* q = (ushort8_t*)(WhT + (size_t)(c0 + cc) * NN + r0 + r8);
  q[0] = o0;
  q[1] = o1;
}

// ---------------- k_dmax ----------------
__global__ __launch_bounds__(256) void k_dmax(const float* __restrict__ dstv,
                                              float* __restrict__ Dp) {
  __shared__ float red[256];
  const int t = threadIdx.x;
  float m = -3e38f;
  for (int i = t; i < NN; i += 256) m = fmaxf(m, dstv[i]);
  red[t] = m;
  __syncthreads();
  for (int s = 128; s >= 1; s >>= 1) {
    if (t < s) red[t] = fmaxf(red[t], red[t + s]);
    __syncthreads();
  }
  if (t == 0) *Dp = red[0];
}

// ---------------- k_attn: pipelined, A-in-LDS (dbuf+swizzle), B direct ----
struct Bset { ushort8_t b[2][2]; };  // [nc][kk]

#define MF(a, b, c) __builtin_amdgcn_mfma_f32_16x16x32_bf16(a, b, c, 0, 0, 0)

// barrier that does NOT drain vmcnt (keeps prefetches in flight)
#define BAR()                                              \
  {                                                        \
    asm volatile("s_waitcnt lgkmcnt(0)" ::: "memory");     \
    __builtin_amdgcn_s_barrier();                          \
    asm volatile("" ::: "memory");                         \
  }

#define LOADB(BS, kt)                                                  \
  {                                                                    \
    const int kb = (kt) * BK + fq * 8;                                 \
    BS.b[0][0] = *(const ushort8_t*)(bp0 + kb);                        \
    BS.b[0][1] = *(const ushort8_t*)(bp0 + kb + 32);                   \
    BS.b[1][0] = *(const ushort8_t*)(bp1 + kb);                        \
    BS.b[1][1] = *(const ushort8_t*)(bp1 + kb + 32);                   \
  }

#define LOADADJ(slot, kt)                                              \
  {                                                                    \
    adjR##slot = *(const int4*)(adjp + (size_t)(kt) * BK);             \
    dR##slot = *(const float4*)(dvp + (kt) * BK);                      \
  }

#define WCOMP(aj, dv, buf, doacc)                                      \
  {                                                                    \
    float w0 = (aj.x > 0) ? __expf(lrelu(s_r + dv.x) - c_r) : 0.f;     \
    float w1 = (aj.y > 0) ? __expf(lrelu(s_r + dv.y) - c_r) : 0.f;     \
    float w2 = (aj.z > 0) ? __expf(lrelu(s_r + dv.z) - c_r) : 0.f;     \
    float w3 = (aj.w > 0) ? __expf(lrelu(s_r + dv.w) - c_r) : 0.f;     \
    unsigned short u0 = f2bf(w0), u1 = f2bf(w1);                       \
    unsigned short u2 = f2bf(w2), u3 = f2bf(w3);                       \
    if (doacc) lsum += bf2f(u0) + bf2f(u1) + bf2f(u2) + bf2f(u3);      \
    uint2 pk;                                                          \
    pk.x = (unsigned)u0 | ((unsigned)u1 << 16);                        \
    pk.y = (unsigned)u2 | ((unsigned)u3 << 16);                        \
    *(uint2*)(sAb + (buf) * 4096 + wbyte) = pk;                        \
  }

#define LDA(cur, mr, kk)                                                        \
  __builtin_bit_cast(bf16x8,                                                    \
    *(const ushort8_t*)(sAb + (cur) * 4096 +                                    \
      ((((mr) * 16 + fr) * 128 + (kk) * 64 + fq * 16) ^ ((fr & 7) << 4))))

#define MSTEP(cur, BS)                                                 \
  {                                                                    \
    bf16x8 a00 = LDA(cur, 0, 0), a01 = LDA(cur, 0, 1);                 \
    bf16x8 a10 = LDA(cur, 1, 0), a11 = LDA(cur, 1, 1);                 \
    acc00 = MF(a00, BS.b[0][0], acc00);                                \
    acc00 = MF(a01, BS.b[0][1], acc00);                                \
    acc01 = MF(a00, BS.b[1][0], acc01);                                \
    acc01 = MF(a01, BS.b[1][1], acc01);                                \
    acc10 = MF(a10, BS.b[0][0], acc10);                                \
    acc10 = MF(a11, BS.b[0][1], acc10);                                \
    acc11 = MF(a10, BS.b[1][0], acc11);                                \
    acc11 = MF(a11, BS.b[1][1], acc11);                                \
  }

__global__ __launch_bounds__(512) void k_attn(const int* __restrict__ adj,
                                              const unsigned short* __restrict__ WhT,
                                              const float* __restrict__ src,
                                              const float* __restrict__ dstv,
                                              const float* __restrict__ Dp,
                                              float* __restrict__ out) {
  __shared__ unsigned short sA[2][32][BK];  // 8 KB, XOR-swizzled rows
  __shared__ float sL[32];
  char* sAb = (char*)&sA[0][0][0];
  const int tid = threadIdx.x;
  const int lane = tid & 63;
  const int wave = tid >> 6;
  const int r0 = blockIdx.x * 32;
  const float D = *Dp;

  // producer role: row pr, 4 cols starting at pj
  const int pr = tid >> 4;
  const int pj = (tid & 15) * 4;
  const float s_r = src[r0 + pr];
  const float c_r = lrelu(s_r + D);
  const int* adjp = adj + (size_t)(r0 + pr) * NN + pj;
  const float* dvp = dstv + pj;
  const int wbyte = ((pr * (BK * 2) + pj * 2) ^ ((pr & 7) << 4));

  // consumer fragment addressing
  const int fr = lane & 15;
  const int fq = lane >> 4;
  const unsigned short* bp0 = WhT + (size_t)(wave * 32 + fr) * NN;
  const unsigned short* bp1 = WhT + (size_t)(wave * 32 + 16 + fr) * NN;

  f32x4 acc00 = {0.f, 0.f, 0.f, 0.f};
  f32x4 acc01 = acc00, acc10 = acc00, acc11 = acc00;
  float lsum = 0.f;

  int4 adjR0, adjR1;
  float4 dR0, dR1;
  Bset B0, B1;

  // prologue: tile 0 inline; prefetch tiles 1 (slot1), 2 (slot0); B(0)
  {
    int4 aT = *(const int4*)adjp;
    float4 dT = *(const float4*)dvp;
    WCOMP(aT, dT, 0, 1);
  }
  LOADADJ(1, 1);
  LOADADJ(0, 2);
  LOADB(B0, 0);
  BAR();

#pragma unroll 1
  for (int t = 0; t < NT; t += 2) {
    // ---- iter t (parity 0): MFMA tile t from buf0, gen tile t+1 -> buf1 ----
    {
      const int tb = (t + 1 < NT) ? t + 1 : NT - 1;
      LOADB(B1, tb);
      MSTEP(0, B0);
      if (t + 1 < NT) { WCOMP(adjR1, dR1, 1, 1); }
      const int tp = (t + 3 < NT) ? t + 3 : NT - 1;
      LOADADJ(1, tp);
      BAR();
    }
    // ---- iter t+1 (parity 1): MFMA tile t+1 from buf1, gen tile t+2 -> buf0 ----
    {
      const int tb = (t + 2 < NT) ? t + 2 : NT - 1;
      LOADB(B0, tb);
      MSTEP(1, B1);
      if (t + 2 < NT) { WCOMP(adjR0, dR0, 0, 1); }
      const int tp = (t + 4 < NT) ? t + 4 : NT - 1;
      LOADADJ(0, tp);
      BAR();
    }
  }

  // row-sum reduce across the 16 threads sharing a row
#pragma unroll
  for (int off = 1; off <= 8; off <<= 1) lsum += __shfl_xor(lsum, off);
  if ((tid & 15) == 0) sL[pr] = lsum;
  __syncthreads();

  // epilogue
  const f32x4 accs[2][2] = {{acc00, acc01}, {acc10, acc11}};
#pragma unroll
  for (int mr = 0; mr < 2; ++mr) {
#pragma unroll
    for (int r = 0; r < 4; ++r) {
      const int row = mr * 16 + fq * 4 + r;
      const float l = sL[row];
#pragma unroll
      for (int nc = 0; nc < 2; ++nc) {
        const int col = wave * 32 + nc * 16 + fr;
        float v = accs[mr][nc][r] / l;
        v = v > 0.f ? v : __expf(v) - 1.f;
        out[(size_t)(r0 + row) * KOUT + col] = v;
      }
    }
  }
}

extern "C" void kernel_launch(void* const* d_in, const int* in_sizes, int n_in,
                              void* d_out, int out_size, void* d_ws, size_t ws_size,
                              hipStream_t stream) {
  const float* h = (const float*)d_in[0];
  const int* adj = (const int*)d_in[1];
  const float* W = (const float*)d_in[2];
  const float* a1 = (const float*)d_in[3];
  const float* a2 = (const float*)d_in[4];
  float* out = (float*)d_out;

  unsigned short* WhB = (unsigned short*)d_ws;
  unsigned short* WhT = WhB + (size_t)NN * KOUT;
  float* src = (float*)(WhT + (size_t)NN * KOUT);
  float* dstv = src + NN;
  float* Dp = dstv + NN;

  hipLaunchKernelGGL(k_wh, dim3(NN / 32), dim3(512), 0, stream, h, W, a1, a2, WhB, src, dstv);
  hipLaunchKernelGGL(k_tr, dim3(512), dim3(256), 0, stream, WhB, WhT);
  hipLaunchKernelGGL(k_dmax, dim3(1), dim3(256), 0, stream, dstv, Dp);
  hipLaunchKernelGGL(k_attn, dim3(NN / 32), dim3(512), 0, stream, adj, WhT, src, dstv, Dp, out);
}